// Round 3
// 58.703 us; speedup vs baseline: 1.1464x; 1.1464x over previous
//
#include <hip/hip_runtime.h>

// Autoregressive bisection inverter, B=512 rows, D=64 dims.
// W is STRICTLY lower triangular, so the bisected scalar function
// g(xi) = softplus(a_i)*xi + sum_{j<i} W[i,j]*tanh(x_j) - y_i
// is linear in xi with positive slope; the exact root is (y_i - c_i)/softplus(a_i)
// whenever it lies in [-10,10].
//
// Key structural fact exploited here: strict lower-triangularity means lane i's
// running residual u_i is FINAL after step i (all later updates multiply W[i,j]=0).
// So at step j, EVERY lane can evaluate the tanh chain from its own local state —
// only lane j's result is meaningful, and it is broadcast AFTER the
// transcendentals. State is pre-scaled: v_i = u_i * (2*log2e / s_i), weights
// w2[j] = W[i][j] * (2*log2e / s_i), so the critical chain per step is just
//   exp2(v) -> +1 -> rcp -> readlane -> fma        (5 dependent ops)
// using t = 1 - 2q, q = 1/(e+1):  v' = v - w2*t = fma(2*w2, q_j, v - w2),
// with (v - w2) and (w2+w2) computed in parallel with the exp2/rcp.
// Roots and the out-of-range check are epilogue-only: x = v / (2*log2e),
// bad  <=>  any lane |x| > 10 (strict), which for monotone linear f is exactly
// sign(f(-10)) == sign(f(10)). Bad rows replay the reference semantics
// (including the lagged-sign adapt_interval bug) in a cold block, reloading W
// from global (keeps hot-loop VGPR footprint at ~one weight copy).

#define DD 64
#define LOWERB (-10.0f)
#define UPPERB (10.0f)
#define K2 2.8853900817779268f      // 2*log2(e)
#define INV_K2 0.34657359027997264f // 1/K2 = ln(2)/2

__device__ __forceinline__ float sgnf(float v) {
    return (v > 0.f) ? 1.f : ((v < 0.f) ? -1.f : 0.f);
}

__device__ __forceinline__ float rl(float v, int l) {
    return __int_as_float(__builtin_amdgcn_readlane(__float_as_int(v), l));
}

// Faithful port of _adapt_interval (incl. lagged-sign evaluation at the
// PRE-update bounds) + _bisection for the linear f(x) = s*x + cmy, s > 0.
__device__ __attribute__((noinline)) float bisect_fallback(float s, float cmy) {
    float lo = LOWERB, up = UPPERB, e = UPPERB - LOWERB;
    float sl = sgnf(fmaf(s, lo, cmy));
    float su = sgnf(fmaf(s, up, cmy));
    int it = 0;
    while (sl == su && it < 200) {
        float nlo = (sl == 1.f) ? (lo - e) : up;
        float nup = (sl == 1.f) ? lo : (up + e);
        float osl = sgnf(fmaf(s, lo, cmy));   // lagged signs (the reference bug)
        float osu = sgnf(fmaf(s, up, cmy));
        lo = nlo; up = nup; e *= 2.f; sl = osl; su = osu; ++it;
    }
    it = 0;
    while ((up - lo) > 2e-6f && it < 200) {
        float mid = 0.5f * (lo + up);
        bool pos = fmaf(s, mid, cmy) >= 0.f;
        if (pos) up = mid; else lo = mid;
        ++it;
    }
    return 0.5f * (lo + up);
}

__global__ __launch_bounds__(256) void ar_invert_kernel(
    const float* __restrict__ y, const float* __restrict__ a,
    const float* __restrict__ W, float* __restrict__ out, int B)
{
    const int lane = threadIdx.x & 63;
    const int row  = (int)((blockIdx.x * 256u + threadIdx.x) >> 6);
    if (row >= B) return;

    // W row of this lane (issued first; latency overlaps the softplus prologue).
    const float4* w4 = (const float4*)(W + lane * DD);
    float4 wv[DD / 4];
    #pragma unroll
    for (int k = 0; k < DD / 4; ++k) wv[k] = w4[k];

    const float u0 = y[row * DD + lane];
    const float av = a[lane];
    const float s  = av + log1pf(expf(-av));   // softplus, a > 0
    const float rs  = 1.f / s;
    const float rs2 = rs * K2;

    // Pre-scaled weights: w2[j] = W[lane][j] * rs2  (zero for j >= lane).
    // wv[] dies here; only the scaled copy stays live through the hot loop.
    float w2[DD];
    #pragma unroll
    for (int k = 0; k < DD / 4; ++k) {
        w2[4 * k + 0] = wv[k].x * rs2; w2[4 * k + 1] = wv[k].y * rs2;
        w2[4 * k + 2] = wv[k].z * rs2; w2[4 * k + 3] = wv[k].w * rs2;
    }

    // Pre-scaled state: v = u * rs2. Lane i's v is final after step i.
    float v = u0 * rs2;

    // Hot loop: critical chain is exp2 -> add -> rcp -> readlane -> fma.
    // All lanes run the tanh chain on their own (possibly not-yet-final) state;
    // only lane j's q is consumed at step j, and for lane j it IS final.
    // exp2 overflow -> e=inf -> q=0 -> t=1; underflow -> q=1 -> t=-1 (both exact).
    #pragma unroll
    for (int j = 0; j < DD; ++j) {
        float e  = __builtin_amdgcn_exp2f(v);
        float q  = __builtin_amdgcn_rcpf(e + 1.f);
        float qj = rl(q, j);
        float vm = v - w2[j];          // off-chain, overlaps exp2/rcp latency
        float d2 = w2[j] + w2[j];      // off-chain
        v = fmaf(d2, qj, vm);          // v - w2*(1 - 2*q_j)
    }

    float x = v * INV_K2;              // every lane's root, in one shot

    // Range check, epilogue-only: strict |x|>10 is exactly the reference's
    // sign(f(lo))==sign(f(up)) trigger for the first offending coordinate
    // (monotone linear f; boundary sign-0 cases fall on the "not bad" side).
    if (__any(fabsf(x) > UPPERB)) {
        // Cold faithful replay from scratch with the reference's buggy
        // adapt-interval + bisection for any out-of-range coordinate.
        // Reload W from global — this path is ~never taken.
        float wr[DD];
        const float4* wg = (const float4*)(W + lane * DD);
        for (int k = 0; k < DD / 4; ++k) {
            float4 t4 = wg[k];
            wr[4 * k + 0] = t4.x; wr[4 * k + 1] = t4.y;
            wr[4 * k + 2] = t4.z; wr[4 * k + 3] = t4.w;
        }
        float u = u0; x = 0.f;
        for (int j = 0; j < DD; ++j) {
            float uj = rl(u, j);
            float sj = rl(s, j);
            float flo = fmaf(sj, LOWERB, -uj);
            float fup = fmaf(sj, UPPERB, -uj);
            float r;
            if (sgnf(flo) == sgnf(fup)) r = bisect_fallback(sj, -uj);
            else                        r = uj * rl(rs, j);
            float t = tanhf(r);
            if (lane == j) x = r;
            u = fmaf(-wr[j], t, u);
        }
    }

    out[row * DD + lane] = x;
}

extern "C" void kernel_launch(void* const* d_in, const int* in_sizes, int n_in,
                              void* d_out, int out_size, void* d_ws, size_t ws_size,
                              hipStream_t stream) {
    const float* y = (const float*)d_in[0];
    const float* a = (const float*)d_in[1];
    const float* W = (const float*)d_in[2];
    float* out = (float*)d_out;
    const int B = in_sizes[0] / DD;          // 512
    const int threads = 256;                 // 4 rows (waves) per block
    const int blocks = (B * DD + threads - 1) / threads;
    ar_invert_kernel<<<blocks, threads, 0, stream>>>(y, a, W, out, B);
}

// Round 6
// 58.207 us; speedup vs baseline: 1.1561x; 1.0085x over previous
//
#include <hip/hip_runtime.h>

// Autoregressive bisection inverter, B=512 rows, D=64 dims.
// W is STRICTLY lower triangular, so the bisected scalar function
// g(xi) = softplus(a_i)*xi + sum_{j<i} W[i,j]*tanh(x_j) - y_i
// is linear in xi with positive slope; the exact root is (y_i - c_i)/softplus(a_i)
// whenever it lies in [-10,10].
//
// Structure (see R0-R3 journal): strict lower-triangularity means lane i's
// pre-scaled residual v_i = u_i * (2*log2e / s_i) is FINAL after step i, so all
// lanes run the tanh chain on their own local state and only the post-
// transcendental broadcast is cross-lane. Per-step recurrence (5 dependent ops,
// the floor for this formula):
//     readlane(q_j) -> fma -> exp2 -> add(+1) -> rcp
// This revision trims issue count & code footprint (cold-I$ regime: the 256 MiB
// harness poison evicts L2+L3 every iteration):
//  - single weight array d2[j] = W[i][j] * (2 * 2*log2e / s_i);
//    vm = fma(-0.5, d2[j], v) reproduces v - w2[j] BITWISE (x2/x0.5 exact),
//    so the hot step is 6 instrs and weight VGPRs halve vs R3.
//  - softplus via v_exp_f32/v_log_f32 intrinsics (no libm calls).
//  - never-taken faithful-replay path exiled to a noinline cold function.
// Out-of-range check is epilogue-only: any |x| > 10 (strict) is exactly the
// reference's sign(f(-10))==sign(f(10)) trigger for monotone linear f.

#define DD 64
#define LOWERB (-10.0f)
#define UPPERB (10.0f)
#define K2 2.8853900817779268f      // 2*log2(e)
#define INV_K2 0.34657359027997264f // 1/K2 = ln(2)/2
#define LOG2E 1.4426950408889634f
#define LN2 0.6931471805599453f

__device__ __forceinline__ float sgnf(float v) {
    return (v > 0.f) ? 1.f : ((v < 0.f) ? -1.f : 0.f);
}

__device__ __forceinline__ float rl(float v, int l) {
    return __int_as_float(__builtin_amdgcn_readlane(__float_as_int(v), l));
}

// Faithful port of _adapt_interval (incl. lagged-sign evaluation at the
// PRE-update bounds) + _bisection for the linear f(x) = s*x + cmy, s > 0.
__device__ __attribute__((noinline)) float bisect_fallback(float s, float cmy) {
    float lo = LOWERB, up = UPPERB, e = UPPERB - LOWERB;
    float sl = sgnf(fmaf(s, lo, cmy));
    float su = sgnf(fmaf(s, up, cmy));
    int it = 0;
    while (sl == su && it < 200) {
        float nlo = (sl == 1.f) ? (lo - e) : up;
        float nup = (sl == 1.f) ? lo : (up + e);
        float osl = sgnf(fmaf(s, lo, cmy));   // lagged signs (the reference bug)
        float osu = sgnf(fmaf(s, up, cmy));
        lo = nlo; up = nup; e *= 2.f; sl = osl; su = osu; ++it;
    }
    it = 0;
    while ((up - lo) > 2e-6f && it < 200) {
        float mid = 0.5f * (lo + up);
        bool pos = fmaf(s, mid, cmy) >= 0.f;
        if (pos) up = mid; else lo = mid;
        ++it;
    }
    return 0.5f * (lo + up);
}

// Cold faithful replay from scratch with the reference's buggy adapt-interval
// + bisection for any out-of-range coordinate. ~Never taken; kept out of the
// hot function's straight-line code.
__device__ __attribute__((noinline)) float cold_replay(
    const float* __restrict__ W, int lane, float u0, float s, float rs)
{
    float wr[DD];
    const float4* wg = (const float4*)(W + lane * DD);
    for (int k = 0; k < DD / 4; ++k) {
        float4 t4 = wg[k];
        wr[4 * k + 0] = t4.x; wr[4 * k + 1] = t4.y;
        wr[4 * k + 2] = t4.z; wr[4 * k + 3] = t4.w;
    }
    float u = u0, x = 0.f;
    for (int j = 0; j < DD; ++j) {
        float uj = rl(u, j);
        float sj = rl(s, j);
        float flo = fmaf(sj, LOWERB, -uj);
        float fup = fmaf(sj, UPPERB, -uj);
        float r;
        if (sgnf(flo) == sgnf(fup)) r = bisect_fallback(sj, -uj);
        else                        r = uj * rl(rs, j);
        float t = tanhf(r);
        if (lane == j) x = r;
        u = fmaf(-wr[j], t, u);
    }
    return x;
}

__global__ __launch_bounds__(256) void ar_invert_kernel(
    const float* __restrict__ y, const float* __restrict__ a,
    const float* __restrict__ W, float* __restrict__ out, int B)
{
    const int lane = threadIdx.x & 63;
    const int row  = (int)((blockIdx.x * 256u + threadIdx.x) >> 6);
    if (row >= B) return;

    // Issue all global loads up front; latency overlaps the softplus chain.
    const float4* w4 = (const float4*)(W + lane * DD);
    float4 wv0 = w4[0], wv1 = w4[1], wv2 = w4[2], wv3 = w4[3];
    float4 wv4 = w4[4], wv5 = w4[5], wv6 = w4[6], wv7 = w4[7];
    float4 wv8 = w4[8], wv9 = w4[9], wva = w4[10], wvb = w4[11];
    float4 wvc = w4[12], wvd = w4[13], wve = w4[14], wvf = w4[15];

    const float u0 = y[row * DD + lane];
    const float av = a[lane];
    // softplus via hw transcendentals: s = a + ln2*log2(1 + exp2(-a*log2e)).
    const float s = fmaf(LN2,
        __builtin_amdgcn_logf(1.f + __builtin_amdgcn_exp2f(-av * LOG2E)), av);
    const float rs  = 1.f / s;
    const float rs4 = rs * (2.f * K2);

    // Single pre-scaled weight array: d2[j] = 2 * W[lane][j] * K2 / s.
    // (j >= lane entries are zero -> the step is a no-op for this lane.)
    float d2[DD];
    {
        const float4 wvs[16] = {wv0,wv1,wv2,wv3,wv4,wv5,wv6,wv7,
                                wv8,wv9,wva,wvb,wvc,wvd,wve,wvf};
        #pragma unroll
        for (int k = 0; k < DD / 4; ++k) {
            d2[4 * k + 0] = wvs[k].x * rs4; d2[4 * k + 1] = wvs[k].y * rs4;
            d2[4 * k + 2] = wvs[k].z * rs4; d2[4 * k + 3] = wvs[k].w * rs4;
        }
    }

    // Pre-scaled state: v = u * (K2/s) = u0 * rs4 * 0.5 (exact halving).
    float v = u0 * rs4 * 0.5f;

    // Hot loop, 6 instrs/step; critical chain: exp2 -> add -> rcp -> readlane -> fma.
    // vm = fma(-0.5, d2, v) == v - w2[j] bitwise (see header comment).
    // exp2 overflow -> e=inf -> q=0 -> t=1; underflow -> q=1 -> t=-1 (both exact).
    #pragma unroll
    for (int j = 0; j < DD; ++j) {
        float e  = __builtin_amdgcn_exp2f(v);
        float q  = __builtin_amdgcn_rcpf(e + 1.f);
        float qj = rl(q, j);
        float vm = fmaf(-0.5f, d2[j], v);  // off-chain, overlaps exp2/rcp
        v = fmaf(d2[j], qj, vm);           // v - w2*(1 - 2*q_j)
    }

    float x = v * INV_K2;                  // every lane's root, in one shot

    // Strict |x|>10 <=> reference's adapt-interval trigger (monotone linear f;
    // boundary sign-0 cases fall on the "not bad" side). Wave-uniform ballot.
    if (__any(fabsf(x) > UPPERB)) {
        x = cold_replay(W, lane, u0, s, rs);
    }

    out[row * DD + lane] = x;
}

extern "C" void kernel_launch(void* const* d_in, const int* in_sizes, int n_in,
                              void* d_out, int out_size, void* d_ws, size_t ws_size,
                              hipStream_t stream) {
    const float* y = (const float*)d_in[0];
    const float* a = (const float*)d_in[1];
    const float* W = (const float*)d_in[2];
    float* out = (float*)d_out;
    const int B = in_sizes[0] / DD;          // 512
    const int threads = 256;                 // 4 rows (waves) per block
    const int blocks = (B * DD + threads - 1) / threads;
    ar_invert_kernel<<<blocks, threads, 0, stream>>>(y, a, W, out, B);
}